// Round 2
// 225.864 us; speedup vs baseline: 1.0599x; 1.0599x over previous
//
#include <hip/hip_runtime.h>

// ---------- types ----------
typedef __bf16 bf16x8 __attribute__((ext_vector_type(8)));
typedef float  f32x4  __attribute__((ext_vector_type(4)));

__device__ __forceinline__ unsigned short f2bf(float f) {
    union { float f; unsigned int u; } x; x.f = f;
    unsigned int r = (x.u + 0x7FFFu + ((x.u >> 16) & 1u)) >> 16;  // RNE
    return (unsigned short)r;
}

// async global->LDS, 16B per lane; LDS dst is wave-uniform base + lane*16
typedef const __attribute__((address_space(1))) unsigned short gu16;
typedef __attribute__((address_space(3)))       unsigned short lu16;
__device__ __forceinline__ void gl_lds16(const unsigned short* g, unsigned short* l) {
    __builtin_amdgcn_global_load_lds((gu16*)g, (lu16*)l, 16, 0, 0);
}

// ==========================================================================
// Double-buffered GEMM core (MF=4): 128x128 tile, BK=32, 4 waves (2x2),
// wave 64x64. Prefetch for iter k+1 issues right after the barrier of iter
// k. LDS: As/Bs = 2 buffers x 8 KB each (32 KB total).
// A [m][k] k-contig (lda), B [n][k] k-contig (ldb). K % 32 == 0.
// Chunk-XOR swizzle (both-sides, rule #21): LDS dest stays linear
// (global_load_lds requirement); the per-lane GLOBAL source chunk is
// pre-permuted so LDS slot (row r, pos p) holds chunk p ^ ((r>>1)&3);
// ds_read applies the same XOR. Read conflicts: 8-way -> 2-way (free).
// ==========================================================================
__device__ __forceinline__ void stage_tiles(
    const unsigned short* __restrict__ Ab, int lda,
    const unsigned short* __restrict__ Bb, int ldb,
    int k0, unsigned short* Ad, unsigned short* Bd,
    int wave, int r0, int c0)
{
    gl_lds16(Ab + (long)r0 * lda + c0 + k0,        Ad + wave * 512);
    gl_lds16(Ab + (long)(r0 + 64) * lda + c0 + k0, Ad + 2048 + wave * 512);
    gl_lds16(Bb + (long)r0 * ldb + c0 + k0,        Bd + wave * 512);
    gl_lds16(Bb + (long)(r0 + 64) * ldb + c0 + k0, Bd + 2048 + wave * 512);
}

__device__ __forceinline__ void gemm_core_db(
    const unsigned short* __restrict__ Ab, int lda,
    const unsigned short* __restrict__ Bb, int ldb,
    int K, f32x4 (&acc)[4][4],
    unsigned short* As, unsigned short* Bs)   // As[2*4096], Bs[2*4096]
{
    const int tid  = threadIdx.x;
    const int lane = tid & 63;
    const int wave = tid >> 6;
    const int wm   = (wave >> 1) * 64;
    const int wn   = (wave & 1) * 64;
    const int l16  = lane & 15;
    const int quad = lane >> 4;

    const int r0 = wave * 16 + (lane >> 2);
    // source chunk pre-swizzle: (r0>>1)&3 == (lane>>3)&3 (wave*16 is 0 mod 8)
    const int c0 = ((lane & 3) ^ ((lane >> 3) & 3)) * 8;

    stage_tiles(Ab, lda, Bb, ldb, 0, As, Bs, wave, r0, c0);

    const int sw8 = ((l16 >> 1) & 3) * 8;     // read-side un-swizzle (ushort units)

    int sel = 0;
    for (int k0 = 0; k0 < K; k0 += 32) {
        __syncthreads();   // buf[sel] arrived (own vmcnt drained; all waves past reads of buf[sel^1])
        if (k0 + 32 < K)
            stage_tiles(Ab, lda, Bb, ldb, k0 + 32,
                        As + (sel ^ 1) * 4096, Bs + (sel ^ 1) * 4096, wave, r0, c0);

        const unsigned short* Ap = As + sel * 4096;
        const unsigned short* Bp = Bs + sel * 4096;
        bf16x8 af[4], bfr[4];
        #pragma unroll
        for (int mi = 0; mi < 4; mi++)
            af[mi] = *(const bf16x8*)&Ap[(wm + mi * 16 + l16) * 32 + ((quad * 8) ^ sw8)];
        #pragma unroll
        for (int ni = 0; ni < 4; ni++)
            bfr[ni] = *(const bf16x8*)&Bp[(wn + ni * 16 + l16) * 32 + ((quad * 8) ^ sw8)];
        #pragma unroll
        for (int mi = 0; mi < 4; mi++)
            #pragma unroll
            for (int ni = 0; ni < 4; ni++)
                acc[mi][ni] = __builtin_amdgcn_mfma_f32_16x16x32_bf16(af[mi], bfr[ni], acc[mi][ni], 0, 0, 0);
        sel ^= 1;
    }
}

// ==========================================================================
// Generic GEMM kernel. EXP_SUM (natural only): C = exp(alpha*acc) bf16 and
// atomicAdd per-row sums into lsum. ROW_SCALE (trans only): scale by
// 1/lsum[n] before store.
// bf16 outputs go through an LDS-bounce epilogue: each wave stages its
// 64x64 tile in its 8KB quarter of the (now dead) staging LDS with an
// XOR-swizzle (2-way max), then emits 8 coalesced 16B stores per lane.
// ==========================================================================
template<typename OutT, bool TRANS_OUT, bool HAS_BIAS, bool HAS_RESID,
         bool EXP_SUM, bool ROW_SCALE>
__global__ __launch_bounds__(256) void gemm_k(
    const unsigned short* __restrict__ Ag, long sA, int lda,
    const unsigned short* __restrict__ Bg, long sB, int ldb,
    OutT* __restrict__ Cg, long sC, int ldc,
    const float* __restrict__ bias,
    const float* __restrict__ resid, long sR,
    float* __restrict__ lsum, long sL,
    float alpha, int K)
{
    __shared__ __align__(16) unsigned short LB[16384];   // 32 KB
    unsigned short* As = LB;
    unsigned short* Bs = LB + 8192;

    const unsigned short* Ab = Ag + (long)blockIdx.z * sA + (long)(blockIdx.y * 128) * lda;
    const unsigned short* Bb = Bg + (long)blockIdx.z * sB + (long)(blockIdx.x * 128) * ldb;

    f32x4 acc[4][4] = {};
    gemm_core_db(Ab, lda, Bb, ldb, K, acc, As, Bs);

    const int lane = threadIdx.x & 63;
    const int wave = threadIdx.x >> 6;
    const int l16  = lane & 15;
    const int quad = lane >> 4;
    const int mb = blockIdx.y * 128 + (wave >> 1) * 64;
    const int nb = blockIdx.x * 128 + (wave & 1) * 64;

    if constexpr (sizeof(OutT) == 2) {
        __syncthreads();                         // all waves done reading As/Bs
        unsigned short* scr = LB + wave * 4096;  // 8 KB per-wave scratch

        #pragma unroll
        for (int mi = 0; mi < 4; mi++) {
            float rsum[4];
            if constexpr (EXP_SUM) { rsum[0] = rsum[1] = rsum[2] = rsum[3] = 0.f; }
            #pragma unroll
            for (int ni = 0; ni < 4; ni++) {
                f32x4 v = acc[mi][ni];
                float invl;
                if constexpr (ROW_SCALE) invl = 1.f / lsum[(long)blockIdx.z * sL + nb + ni * 16 + l16];
                float o[4];
                #pragma unroll
                for (int r = 0; r < 4; r++) {
                    float val = v[r] * alpha;
                    if constexpr (HAS_BIAS) val += bias[mb + mi * 16 + quad * 4 + r];
                    if constexpr (EXP_SUM) { val = __expf(val); rsum[r] += val; }
                    if constexpr (ROW_SCALE) val *= invl;
                    o[r] = val;
                }
                if constexpr (TRANS_OUT) {
                    // scratch layout [n_loc 64][m chunks of 8 ushort], chunk XOR n_loc&7
                    const int nl = ni * 16 + l16;
                    const int ch = mi * 2 + (quad >> 1);
                    ushort4 p; p.x = f2bf(o[0]); p.y = f2bf(o[1]); p.z = f2bf(o[2]); p.w = f2bf(o[3]);
                    *(ushort4*)&scr[nl * 64 + ((ch ^ (nl & 7)) * 8) + (quad & 1) * 4] = p;
                } else {
                    // scratch layout [m_loc 64][n chunks of 8 ushort], chunk XOR m_loc&7
                    #pragma unroll
                    for (int r = 0; r < 4; r++) {
                        const int ml = mi * 16 + quad * 4 + r;
                        const int nc = ni * 2 + (l16 >> 3);
                        scr[ml * 64 + ((nc ^ (ml & 7)) * 8) + (l16 & 7)] = f2bf(o[r]);
                    }
                }
            }
            if constexpr (EXP_SUM) {
                const int m0 = mb + mi * 16 + quad * 4;
                #pragma unroll
                for (int r = 0; r < 4; r++) {
                    float s = rsum[r];
                    s += __shfl_xor(s, 1); s += __shfl_xor(s, 2);
                    s += __shfl_xor(s, 4); s += __shfl_xor(s, 8);
                    if (l16 == 0)
                        atomicAdd(&lsum[(long)blockIdx.z * sL + m0 + r], s);
                }
            }
        }
        __syncthreads();

        const int ch2 = lane & 7;
        const int rr  = lane >> 3;
        unsigned short* Cs = (unsigned short*)Cg + (long)blockIdx.z * sC;
        if constexpr (TRANS_OUT) {
            unsigned short* dst = Cs + mb + ch2 * 8;
            #pragma unroll
            for (int it = 0; it < 8; it++) {
                const int nl = rr + it * 8;
                uint4 v = *(uint4*)&scr[nl * 64 + ((ch2 ^ (nl & 7)) * 8)];
                *(uint4*)(dst + (long)(nb + nl) * ldc) = v;
            }
        } else {
            unsigned short* dst = Cs + nb + ch2 * 8;
            #pragma unroll
            for (int it = 0; it < 8; it++) {
                const int ml = rr + it * 8;
                uint4 v = *(uint4*)&scr[ml * 64 + ((ch2 ^ (ml & 7)) * 8)];
                *(uint4*)(dst + (long)(mb + ml) * ldc) = v;
            }
        }
    } else {
        // fp32 direct path (final gemm): 16 lanes x 4B = full 64B lines, keep direct
        #pragma unroll
        for (int mi = 0; mi < 4; mi++) {
            #pragma unroll
            for (int ni = 0; ni < 4; ni++) {
                f32x4 v = acc[mi][ni];
                const int m0 = mb + mi * 16 + quad * 4;
                const int n  = nb + ni * 16 + l16;
                const long base = (long)blockIdx.z * sC;
                #pragma unroll
                for (int r = 0; r < 4; r++) {
                    float val = v[r] * alpha;
                    if (HAS_BIAS) val += bias[m0 + r];
                    if (HAS_RESID) val += resid[(long)blockIdx.z * sR + (long)(m0 + r) * ldc + n];
                    ((float*)Cg)[base + (long)(m0 + r) * ldc + n] = val;
                }
            }
        }
    }
}

// ==========================================================================
// Fused QKV GEMM: A = Wqkv [1536][512] (wq|wk|wv), B = xnT [n][c].
// blockIdx.y 0..3 -> qT (trans), 4..7 -> kT (trans), 8..11 -> vB (natural).
// Grid (8, 12, 16) = 1536 blocks. LDS-bounce epilogue as in gemm_k.
// ==========================================================================
__global__ __launch_bounds__(256) void qkv_k(
    const unsigned short* __restrict__ Wqkv,
    const unsigned short* __restrict__ xnT,
    unsigned short* __restrict__ qT,
    unsigned short* __restrict__ kT,
    unsigned short* __restrict__ vB,
    const float* __restrict__ bqkv)
{
    __shared__ __align__(16) unsigned short LB[16384];
    unsigned short* As = LB;
    unsigned short* Bs = LB + 8192;

    const unsigned short* Ab = Wqkv + (long)(blockIdx.y * 128) * 512;
    const unsigned short* Bb = xnT + (long)blockIdx.z * 524288 + (long)(blockIdx.x * 128) * 512;

    f32x4 acc[4][4] = {};
    gemm_core_db(Ab, 512, Bb, 512, 512, acc, As, Bs);

    const int lane = threadIdx.x & 63;
    const int wave = threadIdx.x >> 6;
    const int l16  = lane & 15;
    const int quad = lane >> 4;
    const int mb = blockIdx.y * 128 + (wave >> 1) * 64;   // global row in [0,1536)
    const int nb = blockIdx.x * 128 + (wave & 1) * 64;
    const int mat = blockIdx.y >> 2;                      // 0=q 1=k 2=v (block-uniform)
    const long zb = (long)blockIdx.z * 524288;

    __syncthreads();
    unsigned short* scr = LB + wave * 4096;

    #pragma unroll
    for (int mi = 0; mi < 4; mi++) {
        #pragma unroll
        for (int ni = 0; ni < 4; ni++) {
            f32x4 v = acc[mi][ni];
            const int m0 = mb + mi * 16 + quad * 4;
            float o[4];
            #pragma unroll
            for (int r = 0; r < 4; r++) o[r] = v[r] + bqkv[m0 + r];
            if (mat == 2) {
                #pragma unroll
                for (int r = 0; r < 4; r++) {
                    const int ml = mi * 16 + quad * 4 + r;
                    const int nc = ni * 2 + (l16 >> 3);
                    scr[ml * 64 + ((nc ^ (ml & 7)) * 8) + (l16 & 7)] = f2bf(o[r]);
                }
            } else {
                const int nl = ni * 16 + l16;
                const int ch = mi * 2 + (quad >> 1);
                ushort4 p; p.x = f2bf(o[0]); p.y = f2bf(o[1]); p.z = f2bf(o[2]); p.w = f2bf(o[3]);
                *(ushort4*)&scr[nl * 64 + ((ch ^ (nl & 7)) * 8) + (quad & 1) * 4] = p;
            }
        }
    }
    __syncthreads();

    const int ch2 = lane & 7;
    const int rr  = lane >> 3;
    const int ml0 = mb & 511;                             // row within matrix
    if (mat == 2) {
        unsigned short* dst = vB + zb + nb + ch2 * 8;
        #pragma unroll
        for (int it = 0; it < 8; it++) {
            const int ml = rr + it * 8;
            uint4 v = *(uint4*)&scr[ml * 64 + ((ch2 ^ (ml & 7)) * 8)];
            *(uint4*)(dst + (long)(ml0 + ml) * 1024) = v;
        }
    } else {
        unsigned short* dst = ((mat == 0) ? qT : kT) + zb + ml0 + ch2 * 8;
        #pragma unroll
        for (int it = 0; it < 8; it++) {
            const int nl = rr + it * 8;
            uint4 v = *(uint4*)&scr[nl * 64 + ((ch2 ^ (nl & 7)) * 8)];
            *(uint4*)(dst + (long)(nb + nl) * 512) = v;
        }
    }
}

// ==========================================================================
// GroupNorm: x[b][c][n] (fp32) -> xnT[b][n][c] (bf16), 32 groups of 16 ch
// ==========================================================================
__global__ __launch_bounds__(256) void gn_k(
    const float* __restrict__ x, const float* __restrict__ gsc,
    const float* __restrict__ gbi, unsigned short* __restrict__ xnT)
{
    __shared__ __align__(16) unsigned short ln[16 * 1024];
    __shared__ float red[8];
    const int b = blockIdx.y, g = blockIdx.x;
    const int tid = threadIdx.x, lane = tid & 63, wv = tid >> 6;

    const float4* x4 = (const float4*)(x + ((long)b * 512 + g * 16) * 1024);
    float4 vals[16];
    float s = 0.f, ss = 0.f;
    #pragma unroll
    for (int i = 0; i < 16; i++) {
        float4 v = x4[tid + i * 256];
        vals[i] = v;
        s  += v.x + v.y + v.z + v.w;
        ss += v.x * v.x + v.y * v.y + v.z * v.z + v.w * v.w;
    }
    for (int o = 32; o; o >>= 1) { s += __shfl_down(s, o); ss += __shfl_down(ss, o); }
    if (lane == 0) { red[wv * 2] = s; red[wv * 2 + 1] = ss; }
    __syncthreads();
    const float S  = red[0] + red[2] + red[4] + red[6];
    const float SS = red[1] + red[3] + red[5] + red[7];
    const float mean = S * (1.f / 16384.f);
    const float var  = SS * (1.f / 16384.f) - mean * mean;
    const float inv  = rsqrtf(var + 1e-5f);

    #pragma unroll
    for (int i = 0; i < 16; i++) {
        const int idx = tid + i * 256;
        const int c   = idx >> 8;
        const float sc = gsc[g * 16 + c] * inv;
        const float bi = gbi[g * 16 + c] - mean * sc;
        float4 v = vals[i];
        ushort4 p;
        p.x = f2bf(v.x * sc + bi); p.y = f2bf(v.y * sc + bi);
        p.z = f2bf(v.z * sc + bi); p.w = f2bf(v.w * sc + bi);
        ((ushort4*)ln)[idx] = p;
    }
    __syncthreads();

    unsigned short* op = xnT + (long)b * 1024 * 512 + g * 16;
    for (int rep = 0; rep < 4; rep++) {
        const int n = rep * 256 + tid;
        union { unsigned short u[16]; uint4 v[2]; } t;
        #pragma unroll
        for (int c = 0; c < 16; c++) t.u[c] = ln[c * 1024 + n];
        *(uint4*)&op[(long)n * 512]     = t.v[0];
        *(uint4*)&op[(long)n * 512 + 8] = t.v[1];
    }
}

// ---------- weights fp32 -> bf16 + bias concat + lsum zero (y==4 path) ----
__global__ __launch_bounds__(256) void wconv_k(
    const float* __restrict__ w0, const float* __restrict__ w1,
    const float* __restrict__ w2, const float* __restrict__ w3,
    const float* __restrict__ b0, const float* __restrict__ b1,
    const float* __restrict__ b2,
    unsigned short* __restrict__ out, float* __restrict__ bqkv,
    float* __restrict__ lsum)
{
    const int m = blockIdx.y;
    const int i = blockIdx.x * 256 + threadIdx.x;
    if (m == 4) {
        if (i < 384) {
            const int which = i >> 7, off = i & 127;
            const float* src = (which == 0) ? b0 : (which == 1) ? b1 : b2;
            ((float4*)bqkv)[i] = ((const float4*)src)[off];
        }
        if (i < 16384) lsum[i] = 0.f;   // zero [16][1024] row-sum buffer
        return;
    }
    const float* src = (m == 0) ? w0 : (m == 1) ? w1 : (m == 2) ? w2 : w3;
    float4 v = ((const float4*)src)[i];
    ushort4 o; o.x = f2bf(v.x); o.y = f2bf(v.y); o.z = f2bf(v.z); o.w = f2bf(v.w);
    ((ushort4*)(out + (long)m * 262144))[i] = o;
}

// ==========================================================================
extern "C" void kernel_launch(void* const* d_in, const int* in_sizes, int n_in,
                              void* d_out, int out_size, void* d_ws, size_t ws_size,
                              hipStream_t stream)
{
    const float* x   = (const float*)d_in[0];
    const float* gsc = (const float*)d_in[1];
    const float* gbi = (const float*)d_in[2];
    const float* wq  = (const float*)d_in[3];
    const float* bq  = (const float*)d_in[4];
    const float* wk  = (const float*)d_in[5];
    const float* bk  = (const float*)d_in[6];
    const float* wv  = (const float*)d_in[7];
    const float* bv  = (const float*)d_in[8];
    const float* wp  = (const float*)d_in[9];
    const float* bp  = (const float*)d_in[10];
    float* out = (float*)d_out;

    char* ws = (char*)d_ws;
    unsigned short* xnT = (unsigned short*)(ws);               // 16 MB [b][n][c]; reused as OT
    unsigned short* qT  = (unsigned short*)(ws + 16777216);    // 16 MB [b][i][c]
    unsigned short* kT  = (unsigned short*)(ws + 33554432);    // 16 MB [b][j][c]
    unsigned short* vB  = (unsigned short*)(ws + 50331648);    // 16 MB [b][c][j]
    unsigned short* Sb  = (unsigned short*)(ws + 67108864);    // 32 MB [b][i][j] bf16 (P' = exp)
    unsigned short* Wb  = (unsigned short*)(ws + 100663296);   // 2 MB: wq|wk|wv|wp bf16
    float*          bqkv= (float*)        (ws + 102760448);    // 6 KB
    float*          Lb  = (float*)        (ws + 102768640);    // 64 KB [b][i] row sums
    unsigned short* OT  = xnT;

    const long sBCN = 512L * 1024;

    wconv_k<<<dim3(256, 5), 256, 0, stream>>>(wq, wk, wv, wp, bq, bk, bv, Wb, bqkv, Lb);
    gn_k<<<dim3(32, 16), 256, 0, stream>>>(x, gsc, gbi, xnT);

    // fused QKV: qT[i][c], kT[j][c], vB[c][j]
    qkv_k<<<dim3(8, 12, 16), 256, 0, stream>>>(Wb, xnT, qT, kT, vB, bqkv);

    // P'[i][j] = exp(q·k/sqrt(512)) -> bf16; Lb[b][i] += row sums (atomics)
    gemm_k<unsigned short, false, false, false, true, false>
        <<<dim3(8, 8, 16), 256, 0, stream>>>(
        qT, sBCN, 512, kT, sBCN, 512, Sb, 1048576L, 1024, nullptr, nullptr, 0,
        Lb, 1024, 0.044194173824159216f, 512);

    // O[c][i] = sum_j v[c][j]*P'[i][j], scaled by 1/Lb[i] -> OT[i][c]
    gemm_k<unsigned short, true, false, false, false, true>
        <<<dim3(8, 4, 16), 256, 0, stream>>>(
        vB, sBCN, 1024, Sb, 1048576L, 1024, OT, sBCN, 512,
        nullptr, nullptr, 0, Lb, 1024, 1.f, 1024);

    // out = Wp * O + bp + x
    gemm_k<float, false, true, true, false, false>
        <<<dim3(8, 4, 16), 256, 0, stream>>>(
        Wb + 786432, 0, 512, OT, sBCN, 512, out, sBCN, 1024, bp, x, sBCN,
        nullptr, 0, 1.f, 512);
}

// Round 4
// 224.402 us; speedup vs baseline: 1.0668x; 1.0065x over previous
//
#include <hip/hip_runtime.h>

// ---------- types ----------
typedef __bf16 bf16x8 __attribute__((ext_vector_type(8)));
typedef float  f32x4  __attribute__((ext_vector_type(4)));

__device__ __forceinline__ unsigned short f2bf(float f) {
    union { float f; unsigned int u; } x; x.f = f;
    unsigned int r = (x.u + 0x7FFFu + ((x.u >> 16) & 1u)) >> 16;  // RNE
    return (unsigned short)r;
}

// async global->LDS, 16B per lane; LDS dst is wave-uniform base + lane*16
typedef const __attribute__((address_space(1))) unsigned short gu16;
typedef __attribute__((address_space(3)))       unsigned short lu16;
__device__ __forceinline__ void gl_lds16(const unsigned short* g, unsigned short* l) {
    __builtin_amdgcn_global_load_lds((gu16*)g, (lu16*)l, 16, 0, 0);
}

// ==========================================================================
// ===================== 256x256 8-phase GEMM core ==========================
// BM=BN=256, BK=64, 8 waves (2M x 4N), 512 threads, LDS 128KB:
//   A: [2 buf][2 half][128 rows][64 k]  at LB + 0      (32768 ushorts)
//   B: same                             at LB + 32768
// Chunk-XOR swizzle (st_16x32 equivalent): LDS dest linear (global_load_lds
// requirement); the per-lane GLOBAL source chunk is pre-permuted with
// ck_src = (l&7) ^ (((l>>5)&1)<<1); ds_read applies ck' = ck ^ (((r>>2)&1)<<1).
// Same involution both sides (rule #21).
// Stage order per K-tile: B0,B1,A0,A1; 7 half-tiles prologue; 1 HT staged
// per phase; counted vmcnt(6) at phases 4/8 only (vmcnt(0) once, last iter).
// Reads: phase1 = all B + A(mi0-3); phase3 = A(mi4-7). Derived-safe:
// every staged region's last reader is >=1 end-barrier earlier.
// ==========================================================================
__device__ __forceinline__ void stage8(
    const unsigned short* __restrict__ Ab, int lda,
    const unsigned short* __restrict__ Bb, int ldb,
    unsigned short* LB, int s, int s_max, int wave, int lane)
{
    if (s >= s_max) return;
    const int tau  = s >> 2;
    const int pi   = s & 3;          // 0:B0 1:B1 2:A0 3:A1
    const int isA  = pi >> 1;
    const int half = pi & 1;
    unsigned short* dst = LB + (isA ? 0 : 32768) + (tau & 1) * 16384 + half * 8192 + wave * 512;
    const unsigned short* src = isA ? Ab : Bb;
    const int ld = isA ? lda : ldb;
    const int R  = half * 128 + wave * 8 + (lane >> 3);
    const int kc = tau * 64 + (((lane & 7) ^ ((lane >> 5) << 1)) << 3);
    gl_lds16(src + (long)R * ld + kc,        dst);
    gl_lds16(src + (long)(R + 64) * ld + kc, dst + 4096);
}

template<int NT>   // K-tiles of 64; NT even
__device__ __forceinline__ void gemm8_core(
    const unsigned short* __restrict__ Ab, int lda,
    const unsigned short* __restrict__ Bb, int ldb,
    f32x4 (&acc)[8][4], unsigned short* LB)
{
    const int tid  = threadIdx.x;
    const int lane = tid & 63;
    const int wave = tid >> 6;
    const int wM   = wave >> 2;
    const int wN   = wave & 3;
    const int l16  = lane & 15;
    const int quad = lane >> 4;
    const int ckx  = quad ^ (((l16 >> 2) & 1) << 1);
    const int aoff = wM * 8192 + l16 * 64 + ckx * 8;                        // + buf*16384 + mi*1024 + kk*32
    const int boff = 32768 + (wN >> 1) * 8192 + ((wN & 1) * 64 + l16) * 64 + ckx * 8;

    #pragma unroll
    for (int s = 0; s < 7; ++s)
        stage8(Ab, lda, Bb, ldb, LB, s, 4 * NT, wave, lane);
    asm volatile("s_waitcnt vmcnt(6)" ::: "memory");
    __builtin_amdgcn_s_barrier();
    __builtin_amdgcn_sched_barrier(0);

    bf16x8 af[4][2], bf[4][2];

#define RD_A(buf, mh)                                                         \
    _Pragma("unroll")                                                         \
    for (int m = 0; m < 4; ++m)                                               \
        _Pragma("unroll")                                                     \
        for (int kk = 0; kk < 2; ++kk)                                        \
            af[m][kk] = *(const bf16x8*)&LB[(buf) * 16384 + aoff + ((mh) * 4 + m) * 1024 + kk * 32];
#define RD_B(buf)                                                             \
    _Pragma("unroll")                                                         \
    for (int n = 0; n < 4; ++n)                                               \
        _Pragma("unroll")                                                     \
        for (int kk = 0; kk < 2; ++kk)                                        \
            bf[n][kk] = *(const bf16x8*)&LB[(buf) * 16384 + boff + n * 1024 + kk * 32];
#define MF(mh, nh)                                                            \
    __builtin_amdgcn_s_setprio(1);                                            \
    _Pragma("unroll")                                                         \
    for (int m = 0; m < 4; ++m)                                               \
        _Pragma("unroll")                                                     \
        for (int n = 0; n < 2; ++n)                                           \
            _Pragma("unroll")                                                 \
            for (int kk = 0; kk < 2; ++kk)                                    \
                acc[(mh)*4+m][(nh)*2+n] = __builtin_amdgcn_mfma_f32_16x16x32_bf16( \
                    af[m][kk], bf[(nh)*2+n][kk], acc[(mh)*4+m][(nh)*2+n], 0, 0, 0); \
    __builtin_amdgcn_s_setprio(0);
#define BARS do { __builtin_amdgcn_s_barrier(); __builtin_amdgcn_sched_barrier(0); } while (0)
#define LGW  do { asm volatile("s_waitcnt lgkmcnt(0)" ::: "memory"); __builtin_amdgcn_sched_barrier(0); } while (0)

    const int NITER = NT / 2;
    for (int i = 0; i < NITER; ++i) {
        const int s0 = 6 + 8 * i;
        // ---- phase 1 (tile 2i, buf0): read all B + A(mh0); stage HT(2i+1,A1)
        RD_B(0) RD_A(0, 0)
        stage8(Ab, lda, Bb, ldb, LB, s0 + 1, 4 * NT, wave, lane);
        BARS; LGW;
        MF(0, 0)
        BARS;
        // ---- phase 2: stage HT(2i+2,B0)
        stage8(Ab, lda, Bb, ldb, LB, s0 + 2, 4 * NT, wave, lane);
        BARS;
        MF(0, 1)
        BARS;
        // ---- phase 3: read A(mh1); stage HT(2i+2,B1)
        RD_A(0, 1)
        stage8(Ab, lda, Bb, ldb, LB, s0 + 3, 4 * NT, wave, lane);
        BARS; LGW;
        MF(1, 0)
        BARS;
        // ---- phase 4: stage HT(2i+2,A0); counted wait for tile 2i+1
        stage8(Ab, lda, Bb, ldb, LB, s0 + 4, 4 * NT, wave, lane);
        BARS;
        MF(1, 1)
        if (i == NITER - 1) { asm volatile("s_waitcnt vmcnt(0)" ::: "memory"); }
        else                { asm volatile("s_waitcnt vmcnt(6)" ::: "memory"); }
        BARS;
        // ---- phase 5 (tile 2i+1, buf1): read all B + A(mh0); stage HT(2i+2,A1)
        RD_B(1) RD_A(1, 0)
        stage8(Ab, lda, Bb, ldb, LB, s0 + 5, 4 * NT, wave, lane);
        BARS; LGW;
        MF(0, 0)
        BARS;
        // ---- phase 6: stage HT(2i+3,B0)
        stage8(Ab, lda, Bb, ldb, LB, s0 + 6, 4 * NT, wave, lane);
        BARS;
        MF(0, 1)
        BARS;
        // ---- phase 7: read A(mh1); stage HT(2i+3,B1)
        RD_A(1, 1)
        stage8(Ab, lda, Bb, ldb, LB, s0 + 7, 4 * NT, wave, lane);
        BARS; LGW;
        MF(1, 0)
        BARS;
        // ---- phase 8: stage HT(2i+3,A0); counted wait for tile 2i+2
        stage8(Ab, lda, Bb, ldb, LB, s0 + 8, 4 * NT, wave, lane);
        BARS;
        MF(1, 1)
        if (i < NITER - 1) { asm volatile("s_waitcnt vmcnt(6)" ::: "memory"); }
        BARS;
    }
#undef RD_A
#undef RD_B
#undef MF
#undef BARS
#undef LGW
}

// ==========================================================================
// P' kernel (256^2 8-phase): Sb[i][j] = exp(alpha * q.k), row sums -> lsum
// grid (4,4,16), 512 threads. Natural bf16 out via per-wave LDS bounce.
// ==========================================================================
__global__ __launch_bounds__(512, 2) void p8_k(
    const unsigned short* __restrict__ qT,
    const unsigned short* __restrict__ kT,
    unsigned short* __restrict__ Sb,
    float* __restrict__ lsum,
    float alpha)
{
    __shared__ __align__(16) unsigned short LB[65536];
    const int z = blockIdx.z;
    const unsigned short* Ab = qT + (long)z * 524288 + (long)(blockIdx.y * 256) * 512;
    const unsigned short* Bb = kT + (long)z * 524288 + (long)(blockIdx.x * 256) * 512;
    f32x4 acc[8][4] = {};
    gemm8_core<8>(Ab, 512, Bb, 512, acc, LB);

    const int lane = threadIdx.x & 63, wave = threadIdx.x >> 6;
    const int wM = wave >> 2, wN = wave & 3;
    const int l16 = lane & 15, quad = lane >> 4;
    const int gm0 = blockIdx.y * 256 + wM * 128;
    const int gn0 = blockIdx.x * 256 + wN * 64;
    unsigned short* scr = LB + wave * 8192;     // 128 rows x 64 ushort, chunk-XOR

    float rs[8][4];
    #pragma unroll
    for (int mi = 0; mi < 8; ++mi) { rs[mi][0] = rs[mi][1] = rs[mi][2] = rs[mi][3] = 0.f; }
    #pragma unroll
    for (int mi = 0; mi < 8; ++mi)
        #pragma unroll
        for (int ni = 0; ni < 4; ++ni) {
            f32x4 v = acc[mi][ni];
            #pragma unroll
            for (int r = 0; r < 4; ++r) {
                float e = __expf(v[r] * alpha);
                rs[mi][r] += e;
                const int row = mi * 16 + quad * 4 + r;
                const int col = ni * 16 + l16;
                scr[row * 64 + (((col >> 3) ^ (row & 7)) << 3) + (col & 7)] = f2bf(e);
            }
        }
    #pragma unroll
    for (int mi = 0; mi < 8; ++mi)
        #pragma unroll
        for (int r = 0; r < 4; ++r) {
            float s = rs[mi][r];
            s += __shfl_xor(s, 1); s += __shfl_xor(s, 2);
            s += __shfl_xor(s, 4); s += __shfl_xor(s, 8);
            if (l16 == 0)
                atomicAdd(&lsum[(long)z * 1024 + gm0 + mi * 16 + quad * 4 + r], s);
        }
    unsigned short* dst = Sb + (long)z * 1048576;
    #pragma unroll
    for (int it = 0; it < 16; ++it) {
        const int row = it * 8 + (lane >> 3);
        const int ck  = lane & 7;
        uint4 vv = *(uint4*)&scr[row * 64 + ((ck ^ (row & 7)) << 3)];
        *(uint4*)&dst[(long)(gm0 + row) * 1024 + gn0 + ck * 8] = vv;
    }
}

// ==========================================================================
// Fused QKV (256^2 8-phase): A = Wqkv [1536][512], B = xnT [n][c].
// blockIdx.y 0-1 -> qT (trans), 2-3 -> kT (trans), 4-5 -> vB (natural).
// grid (4,6,16), 512 threads.
// ==========================================================================
__global__ __launch_bounds__(512, 2) void qkv8_k(
    const unsigned short* __restrict__ Wqkv,
    const unsigned short* __restrict__ xnT,
    unsigned short* __restrict__ qT,
    unsigned short* __restrict__ kT,
    unsigned short* __restrict__ vB,
    const float* __restrict__ bqkv)
{
    __shared__ __align__(16) unsigned short LB[65536];
    const int z = blockIdx.z;
    const unsigned short* Ab = Wqkv + (long)(blockIdx.y * 256) * 512;
    const unsigned short* Bb = xnT + (long)z * 524288 + (long)(blockIdx.x * 256) * 512;
    f32x4 acc[8][4] = {};
    gemm8_core<8>(Ab, 512, Bb, 512, acc, LB);

    const int lane = threadIdx.x & 63, wave = threadIdx.x >> 6;
    const int wM = wave >> 2, wN = wave & 3;
    const int l16 = lane & 15, quad = lane >> 4;
    const int gm0 = blockIdx.y * 256 + wM * 128;
    const int gn0 = blockIdx.x * 256 + wN * 64;
    const int mat = blockIdx.y >> 1;            // 0=q 1=k 2=v (block-uniform)
    const int ml0 = gm0 & 511;
    const long zb = (long)z * 524288;
    unsigned short* scr = LB + wave * 8192;

    if (mat == 2) {
        // natural -> vB[c][j]
        #pragma unroll
        for (int mi = 0; mi < 8; ++mi)
            #pragma unroll
            for (int ni = 0; ni < 4; ++ni) {
                f32x4 v = acc[mi][ni];
                #pragma unroll
                for (int r = 0; r < 4; ++r) {
                    const int row = mi * 16 + quad * 4 + r;
                    const int col = ni * 16 + l16;
                    scr[row * 64 + (((col >> 3) ^ (row & 7)) << 3) + (col & 7)] =
                        f2bf(v[r] + bqkv[gm0 + row]);
                }
            }
        #pragma unroll
        for (int it = 0; it < 16; ++it) {
            const int row = it * 8 + (lane >> 3);
            const int ck  = lane & 7;
            uint4 vv = *(uint4*)&scr[row * 64 + ((ck ^ (row & 7)) << 3)];
            *(uint4*)&vB[zb + (long)(ml0 + row) * 1024 + gn0 + ck * 8] = vv;
        }
    } else {
        // trans -> qT/kT [i][c]; scratch [col 64][16 chunks of 8 rows], XOR nl&15
        unsigned short* dstm = (mat == 0) ? qT : kT;
        #pragma unroll
        for (int mi = 0; mi < 8; ++mi)
            #pragma unroll
            for (int ni = 0; ni < 4; ++ni) {
                f32x4 v = acc[mi][ni];
                const int nl = ni * 16 + l16;
                const int ch = mi * 2 + (quad >> 1);
                const int m4 = gm0 + mi * 16 + quad * 4;
                ushort4 p;
                p.x = f2bf(v[0] + bqkv[m4 + 0]);
                p.y = f2bf(v[1] + bqkv[m4 + 1]);
                p.z = f2bf(v[2] + bqkv[m4 + 2]);
                p.w = f2bf(v[3] + bqkv[m4 + 3]);
                *(ushort4*)&scr[nl * 128 + ((ch ^ (nl & 15)) << 3) + (quad & 1) * 4] = p;
            }
        #pragma unroll
        for (int it = 0; it < 16; ++it) {
            const int nl  = it * 4 + (lane >> 4);
            const int chl = lane & 15;
            uint4 vv = *(uint4*)&scr[nl * 128 + ((chl ^ (nl & 15)) << 3)];
            *(uint4*)&dstm[zb + (long)(gn0 + nl) * 512 + ml0 + chl * 8] = vv;
        }
    }
}

// ==========================================================================
// ============== 128x128 2-phase core (AV + final gemms) ===================
// ==========================================================================
__device__ __forceinline__ void stage_tiles(
    const unsigned short* __restrict__ Ab, int lda,
    const unsigned short* __restrict__ Bb, int ldb,
    int k0, unsigned short* Ad, unsigned short* Bd,
    int wave, int r0, int c0)
{
    gl_lds16(Ab + (long)r0 * lda + c0 + k0,        Ad + wave * 512);
    gl_lds16(Ab + (long)(r0 + 64) * lda + c0 + k0, Ad + 2048 + wave * 512);
    gl_lds16(Bb + (long)r0 * ldb + c0 + k0,        Bd + wave * 512);
    gl_lds16(Bb + (long)(r0 + 64) * ldb + c0 + k0, Bd + 2048 + wave * 512);
}

__device__ __forceinline__ void gemm_core_db(
    const unsigned short* __restrict__ Ab, int lda,
    const unsigned short* __restrict__ Bb, int ldb,
    int K, f32x4 (&acc)[4][4],
    unsigned short* As, unsigned short* Bs)   // As[2*4096], Bs[2*4096]
{
    const int tid  = threadIdx.x;
    const int lane = tid & 63;
    const int wave = tid >> 6;
    const int wm   = (wave >> 1) * 64;
    const int wn   = (wave & 1) * 64;
    const int l16  = lane & 15;
    const int quad = lane >> 4;

    const int r0 = wave * 16 + (lane >> 2);
    const int c0 = ((lane & 3) ^ ((lane >> 3) & 3)) * 8;   // source chunk pre-swizzle

    stage_tiles(Ab, lda, Bb, ldb, 0, As, Bs, wave, r0, c0);

    const int sw8 = ((l16 >> 1) & 3) * 8;     // read-side un-swizzle

    int sel = 0;
    for (int k0 = 0; k0 < K; k0 += 32) {
        __syncthreads();
        if (k0 + 32 < K)
            stage_tiles(Ab, lda, Bb, ldb, k0 + 32,
                        As + (sel ^ 1) * 4096, Bs + (sel ^ 1) * 4096, wave, r0, c0);

        const unsigned short* Ap = As + sel * 4096;
        const unsigned short* Bp = Bs + sel * 4096;
        bf16x8 af[4], bfr[4];
        #pragma unroll
        for (int mi = 0; mi < 4; mi++)
            af[mi] = *(const bf16x8*)&Ap[(wm + mi * 16 + l16) * 32 + ((quad * 8) ^ sw8)];
        #pragma unroll
        for (int ni = 0; ni < 4; ni++)
            bfr[ni] = *(const bf16x8*)&Bp[(wn + ni * 16 + l16) * 32 + ((quad * 8) ^ sw8)];
        #pragma unroll
        for (int mi = 0; mi < 4; mi++)
            #pragma unroll
            for (int ni = 0; ni < 4; ni++)
                acc[mi][ni] = __builtin_amdgcn_mfma_f32_16x16x32_bf16(af[mi], bfr[ni], acc[mi][ni], 0, 0, 0);
        sel ^= 1;
    }
}

template<typename OutT, bool TRANS_OUT, bool HAS_BIAS, bool HAS_RESID,
         bool EXP_SUM, bool ROW_SCALE>
__global__ __launch_bounds__(256) void gemm_k(
    const unsigned short* __restrict__ Ag, long sA, int lda,
    const unsigned short* __restrict__ Bg, long sB, int ldb,
    OutT* __restrict__ Cg, long sC, int ldc,
    const float* __restrict__ bias,
    const float* __restrict__ resid, long sR,
    float* __restrict__ lsum, long sL,
    float alpha, int K)
{
    __shared__ __align__(16) unsigned short LB[16384];   // 32 KB
    unsigned short* As = LB;
    unsigned short* Bs = LB + 8192;

    const unsigned short* Ab = Ag + (long)blockIdx.z * sA + (long)(blockIdx.y * 128) * lda;
    const unsigned short* Bb = Bg + (long)blockIdx.z * sB + (long)(blockIdx.x * 128) * ldb;

    f32x4 acc[4][4] = {};
    gemm_core_db(Ab, lda, Bb, ldb, K, acc, As, Bs);

    const int lane = threadIdx.x & 63;
    const int wave = threadIdx.x >> 6;
    const int l16  = lane & 15;
    const int quad = lane >> 4;
    const int mb = blockIdx.y * 128 + (wave >> 1) * 64;
    const int nb = blockIdx.x * 128 + (wave & 1) * 64;

    if constexpr (sizeof(OutT) == 2) {
        __syncthreads();                         // all waves done reading As/Bs
        unsigned short* scr = LB + wave * 4096;  // 8 KB per-wave scratch

        #pragma unroll
        for (int mi = 0; mi < 4; mi++) {
            float rsum[4];
            if constexpr (EXP_SUM) { rsum[0] = rsum[1] = rsum[2] = rsum[3] = 0.f; }
            #pragma unroll
            for (int ni = 0; ni < 4; ni++) {
                f32x4 v = acc[mi][ni];
                float invl;
                if constexpr (ROW_SCALE) invl = 1.f / lsum[(long)blockIdx.z * sL + nb + ni * 16 + l16];
                float o[4];
                #pragma unroll
                for (int r = 0; r < 4; r++) {
                    float val = v[r] * alpha;
                    if constexpr (HAS_BIAS) val += bias[mb + mi * 16 + quad * 4 + r];
                    if constexpr (EXP_SUM) { val = __expf(val); rsum[r] += val; }
                    if constexpr (ROW_SCALE) val *= invl;
                    o[r] = val;
                }
                if constexpr (TRANS_OUT) {
                    const int nl = ni * 16 + l16;
                    const int ch = mi * 2 + (quad >> 1);
                    ushort4 p; p.x = f2bf(o[0]); p.y = f2bf(o[1]); p.z = f2bf(o[2]); p.w = f2bf(o[3]);
                    *(ushort4*)&scr[nl * 64 + ((ch ^ (nl & 7)) * 8) + (quad & 1) * 4] = p;
                } else {
                    #pragma unroll
                    for (int r = 0; r < 4; r++) {
                        const int ml = mi * 16 + quad * 4 + r;
                        const int nc = ni * 2 + (l16 >> 3);
                        scr[ml * 64 + ((nc ^ (ml & 7)) * 8) + (l16 & 7)] = f2bf(o[r]);
                    }
                }
            }
            if constexpr (EXP_SUM) {
                const int m0 = mb + mi * 16 + quad * 4;
                #pragma unroll
                for (int r = 0; r < 4; r++) {
                    float s = rsum[r];
                    s += __shfl_xor(s, 1); s += __shfl_xor(s, 2);
                    s += __shfl_xor(s, 4); s += __shfl_xor(s, 8);
                    if (l16 == 0)
                        atomicAdd(&lsum[(long)blockIdx.z * sL + m0 + r], s);
                }
            }
        }
        __syncthreads();

        const int ch2 = lane & 7;
        const int rr  = lane >> 3;
        unsigned short* Cs = (unsigned short*)Cg + (long)blockIdx.z * sC;
        if constexpr (TRANS_OUT) {
            unsigned short* dst = Cs + mb + ch2 * 8;
            #pragma unroll
            for (int it = 0; it < 8; it++) {
                const int nl = rr + it * 8;
                uint4 v = *(uint4*)&scr[nl * 64 + ((ch2 ^ (nl & 7)) * 8)];
                *(uint4*)(dst + (long)(nb + nl) * ldc) = v;
            }
        } else {
            unsigned short* dst = Cs + nb + ch2 * 8;
            #pragma unroll
            for (int it = 0; it < 8; it++) {
                const int ml = rr + it * 8;
                uint4 v = *(uint4*)&scr[ml * 64 + ((ch2 ^ (ml & 7)) * 8)];
                *(uint4*)(dst + (long)(mb + ml) * ldc) = v;
            }
        }
    } else {
        // fp32 direct path (final gemm)
        #pragma unroll
        for (int mi = 0; mi < 4; mi++) {
            #pragma unroll
            for (int ni = 0; ni < 4; ni++) {
                f32x4 v = acc[mi][ni];
                const int m0 = mb + mi * 16 + quad * 4;
                const int n  = nb + ni * 16 + l16;
                const long base = (long)blockIdx.z * sC;
                #pragma unroll
                for (int r = 0; r < 4; r++) {
                    float val = v[r] * alpha;
                    if (HAS_BIAS) val += bias[m0 + r];
                    if (HAS_RESID) val += resid[(long)blockIdx.z * sR + (long)(m0 + r) * ldc + n];
                    ((float*)Cg)[base + (long)(m0 + r) * ldc + n] = val;
                }
            }
        }
    }
}

// ==========================================================================
// GroupNorm: x[b][c][n] (fp32) -> xnT[b][n][c] (bf16), 32 groups of 16 ch
// ==========================================================================
__global__ __launch_bounds__(256) void gn_k(
    const float* __restrict__ x, const float* __restrict__ gsc,
    const float* __restrict__ gbi, unsigned short* __restrict__ xnT)
{
    __shared__ __align__(16) unsigned short ln[16 * 1024];
    __shared__ float red[8];
    const int b = blockIdx.y, g = blockIdx.x;
    const int tid = threadIdx.x, lane = tid & 63, wv = tid >> 6;

    const float4* x4 = (const float4*)(x + ((long)b * 512 + g * 16) * 1024);
    float4 vals[16];
    float s = 0.f, ss = 0.f;
    #pragma unroll
    for (int i = 0; i < 16; i++) {
        float4 v = x4[tid + i * 256];
        vals[i] = v;
        s  += v.x + v.y + v.z + v.w;
        ss += v.x * v.x + v.y * v.y + v.z * v.z + v.w * v.w;
    }
    for (int o = 32; o; o >>= 1) { s += __shfl_down(s, o); ss += __shfl_down(ss, o); }
    if (lane == 0) { red[wv * 2] = s; red[wv * 2 + 1] = ss; }
    __syncthreads();
    const float S  = red[0] + red[2] + red[4] + red[6];
    const float SS = red[1] + red[3] + red[5] + red[7];
    const float mean = S * (1.f / 16384.f);
    const float var  = SS * (1.f / 16384.f) - mean * mean;
    const float inv  = rsqrtf(var + 1e-5f);

    #pragma unroll
    for (int i = 0; i < 16; i++) {
        const int idx = tid + i * 256;
        const int c   = idx >> 8;
        const float sc = gsc[g * 16 + c] * inv;
        const float bi = gbi[g * 16 + c] - mean * sc;
        float4 v = vals[i];
        ushort4 p;
        p.x = f2bf(v.x * sc + bi); p.y = f2bf(v.y * sc + bi);
        p.z = f2bf(v.z * sc + bi); p.w = f2bf(v.w * sc + bi);
        ((ushort4*)ln)[idx] = p;
    }
    __syncthreads();

    unsigned short* op = xnT + (long)b * 1024 * 512 + g * 16;
    for (int rep = 0; rep < 4; rep++) {
        const int n = rep * 256 + tid;
        union { unsigned short u[16]; uint4 v[2]; } t;
        #pragma unroll
        for (int c = 0; c < 16; c++) t.u[c] = ln[c * 1024 + n];
        *(uint4*)&op[(long)n * 512]     = t.v[0];
        *(uint4*)&op[(long)n * 512 + 8] = t.v[1];
    }
}

// ---------- weights fp32 -> bf16 + bias concat + lsum zero (y==4 path) ----
__global__ __launch_bounds__(256) void wconv_k(
    const float* __restrict__ w0, const float* __restrict__ w1,
    const float* __restrict__ w2, const float* __restrict__ w3,
    const float* __restrict__ b0, const float* __restrict__ b1,
    const float* __restrict__ b2,
    unsigned short* __restrict__ out, float* __restrict__ bqkv,
    float* __restrict__ lsum)
{
    const int m = blockIdx.y;
    const int i = blockIdx.x * 256 + threadIdx.x;
    if (m == 4) {
        if (i < 384) {
            const int which = i >> 7, off = i & 127;
            const float* src = (which == 0) ? b0 : (which == 1) ? b1 : b2;
            ((float4*)bqkv)[i] = ((const float4*)src)[off];
        }
        if (i < 16384) lsum[i] = 0.f;   // zero [16][1024] row-sum buffer
        return;
    }
    const float* src = (m == 0) ? w0 : (m == 1) ? w1 : (m == 2) ? w2 : w3;
    float4 v = ((const float4*)src)[i];
    ushort4 o; o.x = f2bf(v.x); o.y = f2bf(v.y); o.z = f2bf(v.z); o.w = f2bf(v.w);
    ((ushort4*)(out + (long)m * 262144))[i] = o;
}

// ==========================================================================
extern "C" void kernel_launch(void* const* d_in, const int* in_sizes, int n_in,
                              void* d_out, int out_size, void* d_ws, size_t ws_size,
                              hipStream_t stream)
{
    const float* x   = (const float*)d_in[0];
    const float* gsc = (const float*)d_in[1];
    const float* gbi = (const float*)d_in[2];
    const float* wq  = (const float*)d_in[3];
    const float* bq  = (const float*)d_in[4];
    const float* wk  = (const float*)d_in[5];
    const float* bk  = (const float*)d_in[6];
    const float* wv  = (const float*)d_in[7];
    const float* bv  = (const float*)d_in[8];
    const float* wp  = (const float*)d_in[9];
    const float* bp  = (const float*)d_in[10];
    float* out = (float*)d_out;

    char* ws = (char*)d_ws;
    unsigned short* xnT = (unsigned short*)(ws);               // 16 MB [b][n][c]; reused as OT
    unsigned short* qT  = (unsigned short*)(ws + 16777216);    // 16 MB [b][i][c]
    unsigned short* kT  = (unsigned short*)(ws + 33554432);    // 16 MB [b][j][c]
    unsigned short* vB  = (unsigned short*)(ws + 50331648);    // 16 MB [b][c][j]
    unsigned short* Sb  = (unsigned short*)(ws + 67108864);    // 32 MB [b][i][j] bf16 (P' = exp)
    unsigned short* Wb  = (unsigned short*)(ws + 100663296);   // 2 MB: wq|wk|wv|wp bf16
    float*          bqkv= (float*)        (ws + 102760448);    // 6 KB
    float*          Lb  = (float*)        (ws + 102768640);    // 64 KB [b][i] row sums
    unsigned short* OT  = xnT;

    const long sBCN = 512L * 1024;

    wconv_k<<<dim3(256, 5), 256, 0, stream>>>(wq, wk, wv, wp, bq, bk, bv, Wb, bqkv, Lb);
    gn_k<<<dim3(32, 16), 256, 0, stream>>>(x, gsc, gbi, xnT);

    // fused QKV (256^2 8-phase): qT[i][c], kT[j][c], vB[c][j]
    qkv8_k<<<dim3(4, 6, 16), 512, 0, stream>>>(Wb, xnT, qT, kT, vB, bqkv);

    // P'[i][j] = exp(q·k/sqrt(512)) -> bf16 (256^2 8-phase); Lb row sums
    p8_k<<<dim3(4, 4, 16), 512, 0, stream>>>(qT, kT, Sb, Lb, 0.044194173824159216f);

    // O[c][i] = sum_j v[c][j]*P'[i][j], scaled by 1/Lb[i] -> OT[i][c]
    gemm_k<unsigned short, true, false, false, false, true>
        <<<dim3(8, 4, 16), 256, 0, stream>>>(
        vB, sBCN, 1024, Sb, 1048576L, 1024, OT, sBCN, 512,
        nullptr, nullptr, 0, Lb, 1024, 1.f, 1024);

    // out = Wp * O + bp + x
    gemm_k<float, false, true, true, false, false>
        <<<dim3(8, 4, 16), 256, 0, stream>>>(
        Wb + 786432, 0, 512, OT, sBCN, 512, out, sBCN, 1024, bp, x, sBCN,
        nullptr, 0, 1.f, 512);
}

// Round 5
// 219.436 us; speedup vs baseline: 1.0910x; 1.0226x over previous
//
#include <hip/hip_runtime.h>

// ---------- types ----------
typedef __bf16 bf16x8 __attribute__((ext_vector_type(8)));
typedef float  f32x4  __attribute__((ext_vector_type(4)));

__device__ __forceinline__ unsigned short f2bf(float f) {
    union { float f; unsigned int u; } x; x.f = f;
    unsigned int r = (x.u + 0x7FFFu + ((x.u >> 16) & 1u)) >> 16;  // RNE
    return (unsigned short)r;
}

// async global->LDS, 16B per lane; LDS dst is wave-uniform base + lane*16
typedef const __attribute__((address_space(1))) unsigned short gu16;
typedef __attribute__((address_space(3)))       unsigned short lu16;
__device__ __forceinline__ void gl_lds16(const unsigned short* g, unsigned short* l) {
    __builtin_amdgcn_global_load_lds((gu16*)g, (lu16*)l, 16, 0, 0);
}

// ==========================================================================
// ============== generic 8-phase GEMM core: BM=128*BMH, BN=256 =============
// 8 waves (2M x 4N), 512 threads. LDS:
//   A: [2 buf][2 half][BM/2 rows][64 k]  at LB + 0        (BM*128 ushorts)
//   B: [2 buf][2 half][128  rows][64 k]  at LB + BM*128   (32768 ushorts)
// Chunk-XOR swizzle (st_16x32): LDS dest linear (global_load_lds reqmt);
// per-lane GLOBAL source chunk pre-permuted ck^=((lane>>5)&1)<<1; ds_read
// applies ck^=((row>>2)&1)<<1 — same involution both sides (rule #21).
// Stage order per K-tile: B0,B1,A0,A1 (B halves 2 loads, A halves BMH).
// 7 half-tiles prologue; 1 HT staged per phase; counted vmcnt(4+BMH) at
// phases 4/8 only (FIFO ledger: outstanding there = next tile's B0+B1+A0
// = 2+2+BMH loads); vmcnt(0) once, in last iteration's phase 4.
// Reads front-loaded (phase1: all B + A lower mh; phase3: A upper mh) so
// every staged region's last reader is >=1 end-barrier before overwrite.
// ==========================================================================
template<int NT, int BMH>
__device__ __forceinline__ void stage8g(
    const unsigned short* __restrict__ Ab, int lda,
    const unsigned short* __restrict__ Bb, int ldb,
    unsigned short* LB, int s, int wave, int lane)
{
    if (s >= 4 * NT) return;
    const int tau  = s >> 2;
    const int pi   = s & 3;          // 0:B0 1:B1 2:A0 3:A1
    const int half = pi & 1;
    const int kc   = tau * 64 + (((lane & 7) ^ ((lane >> 5) << 1)) << 3);
    if (pi >= 2) {   // A: BM/2 = 64*BMH rows per half, BMH loads/lane
        unsigned short* dst = LB + (tau & 1) * (BMH * 8192) + half * (BMH * 4096) + wave * 512;
        const int R = half * (BMH * 64) + wave * 8 + (lane >> 3);
        gl_lds16(Ab + (long)R * lda + kc, dst);
        if constexpr (BMH == 2) gl_lds16(Ab + (long)(R + 64) * lda + kc, dst + 4096);
    } else {         // B: 128 rows per half, 2 loads/lane
        unsigned short* dst = LB + (BMH * 16384) + (tau & 1) * 16384 + half * 8192 + wave * 512;
        const int R = half * 128 + wave * 8 + (lane >> 3);
        gl_lds16(Bb + (long)R * ldb + kc, dst);
        gl_lds16(Bb + (long)(R + 64) * ldb + kc, dst + 4096);
    }
}

template<int NT, int BMH>   // NT = K/64, even
__device__ __forceinline__ void gemm8_core(
    const unsigned short* __restrict__ Ab, int lda,
    const unsigned short* __restrict__ Bb, int ldb,
    f32x4 (&acc)[4 * BMH][4], unsigned short* LB)
{
    const int tid  = threadIdx.x;
    const int lane = tid & 63;
    const int wave = tid >> 6;
    const int wM   = wave >> 2;
    const int wN   = wave & 3;
    const int l16  = lane & 15;
    const int quad = lane >> 4;
    const int ckx  = quad ^ (((l16 >> 2) & 1) << 1);
    const int aoff = wM * (BMH * 4096) + l16 * 64 + ckx * 8;   // + buf*(BMH*8192) + mi*1024 + kk*32
    const int boff = BMH * 16384 + (wN >> 1) * 8192 + ((wN & 1) * 64 + l16) * 64 + ckx * 8;

#define VMW do { if constexpr (BMH == 2) asm volatile("s_waitcnt vmcnt(6)" ::: "memory"); \
                 else                    asm volatile("s_waitcnt vmcnt(5)" ::: "memory"); } while (0)

    #pragma unroll
    for (int s = 0; s < 7; ++s)
        stage8g<NT, BMH>(Ab, lda, Bb, ldb, LB, s, wave, lane);
    VMW;
    __builtin_amdgcn_s_barrier();
    __builtin_amdgcn_sched_barrier(0);

    bf16x8 af[2 * BMH][2], bf[4][2];

#define RD_A(buf, mh)                                                         \
    _Pragma("unroll")                                                         \
    for (int m = 0; m < 2 * BMH; ++m)                                         \
        _Pragma("unroll")                                                     \
        for (int kk = 0; kk < 2; ++kk)                                        \
            af[m][kk] = *(const bf16x8*)&LB[(buf) * (BMH * 8192) + aoff + ((mh) * 2 * BMH + m) * 1024 + kk * 32];
#define RD_B(buf)                                                             \
    _Pragma("unroll")                                                         \
    for (int n = 0; n < 4; ++n)                                               \
        _Pragma("unroll")                                                     \
        for (int kk = 0; kk < 2; ++kk)                                        \
            bf[n][kk] = *(const bf16x8*)&LB[(buf) * 16384 + boff + n * 1024 + kk * 32];
#define MF(mh, nh)                                                            \
    __builtin_amdgcn_s_setprio(1);                                            \
    _Pragma("unroll")                                                         \
    for (int m = 0; m < 2 * BMH; ++m)                                         \
        _Pragma("unroll")                                                     \
        for (int n = 0; n < 2; ++n)                                           \
            _Pragma("unroll")                                                 \
            for (int kk = 0; kk < 2; ++kk)                                    \
                acc[(mh) * 2 * BMH + m][(nh) * 2 + n] = __builtin_amdgcn_mfma_f32_16x16x32_bf16( \
                    af[m][kk], bf[(nh) * 2 + n][kk], acc[(mh) * 2 * BMH + m][(nh) * 2 + n], 0, 0, 0); \
    __builtin_amdgcn_s_setprio(0);
#define BARS do { __builtin_amdgcn_s_barrier(); __builtin_amdgcn_sched_barrier(0); } while (0)
#define LGW  do { asm volatile("s_waitcnt lgkmcnt(0)" ::: "memory"); __builtin_amdgcn_sched_barrier(0); } while (0)

    const int NITER = NT / 2;
    for (int i = 0; i < NITER; ++i) {
        const int s0 = 6 + 8 * i;
        // ---- phase 1 (tile 2i, buf0): read all B + A(mh0); stage HT(2i+1,A1)
        RD_B(0) RD_A(0, 0)
        stage8g<NT, BMH>(Ab, lda, Bb, ldb, LB, s0 + 1, wave, lane);
        BARS; LGW;
        MF(0, 0)
        BARS;
        // ---- phase 2: stage HT(2i+2,B0)
        stage8g<NT, BMH>(Ab, lda, Bb, ldb, LB, s0 + 2, wave, lane);
        BARS;
        MF(0, 1)
        BARS;
        // ---- phase 3: read A(mh1); stage HT(2i+2,B1)
        RD_A(0, 1)
        stage8g<NT, BMH>(Ab, lda, Bb, ldb, LB, s0 + 3, wave, lane);
        BARS; LGW;
        MF(1, 0)
        BARS;
        // ---- phase 4: stage HT(2i+2,A0); counted wait for tile 2i+1
        stage8g<NT, BMH>(Ab, lda, Bb, ldb, LB, s0 + 4, wave, lane);
        BARS;
        MF(1, 1)
        if (i == NITER - 1) { asm volatile("s_waitcnt vmcnt(0)" ::: "memory"); }
        else                { VMW; }
        BARS;
        // ---- phase 5 (tile 2i+1, buf1): read all B + A(mh0); stage HT(2i+2,A1)
        RD_B(1) RD_A(1, 0)
        stage8g<NT, BMH>(Ab, lda, Bb, ldb, LB, s0 + 5, wave, lane);
        BARS; LGW;
        MF(0, 0)
        BARS;
        // ---- phase 6: stage HT(2i+3,B0)
        stage8g<NT, BMH>(Ab, lda, Bb, ldb, LB, s0 + 6, wave, lane);
        BARS;
        MF(0, 1)
        BARS;
        // ---- phase 7: read A(mh1); stage HT(2i+3,B1)
        RD_A(1, 1)
        stage8g<NT, BMH>(Ab, lda, Bb, ldb, LB, s0 + 7, wave, lane);
        BARS; LGW;
        MF(1, 0)
        BARS;
        // ---- phase 8: stage HT(2i+3,A0); counted wait for tile 2i+2
        stage8g<NT, BMH>(Ab, lda, Bb, ldb, LB, s0 + 8, wave, lane);
        BARS;
        MF(1, 1)
        if (i < NITER - 1) { VMW; }
        BARS;
    }
#undef RD_A
#undef RD_B
#undef MF
#undef BARS
#undef LGW
#undef VMW
}

// ==========================================================================
// P' kernel (256^2 8-phase): Sb[i][j] = exp(alpha * q.k), row sums -> lsum
// grid (4,4,16) = 256 blocks, 512 threads.
// ==========================================================================
__global__ __launch_bounds__(512, 2) void p8_k(
    const unsigned short* __restrict__ qT,
    const unsigned short* __restrict__ kT,
    unsigned short* __restrict__ Sb,
    float* __restrict__ lsum,
    float alpha)
{
    __shared__ __align__(16) unsigned short LB[65536];
    const int z = blockIdx.z;
    const unsigned short* Ab = qT + (long)z * 524288 + (long)(blockIdx.y * 256) * 512;
    const unsigned short* Bb = kT + (long)z * 524288 + (long)(blockIdx.x * 256) * 512;
    f32x4 acc[8][4] = {};
    gemm8_core<8, 2>(Ab, 512, Bb, 512, acc, LB);

    const int lane = threadIdx.x & 63, wave = threadIdx.x >> 6;
    const int wM = wave >> 2, wN = wave & 3;
    const int l16 = lane & 15, quad = lane >> 4;
    const int gm0 = blockIdx.y * 256 + wM * 128;
    const int gn0 = blockIdx.x * 256 + wN * 64;
    unsigned short* scr = LB + wave * 8192;     // 128 rows x 64 ushort, chunk-XOR

    float rs[8][4];
    #pragma unroll
    for (int mi = 0; mi < 8; ++mi) { rs[mi][0] = rs[mi][1] = rs[mi][2] = rs[mi][3] = 0.f; }
    #pragma unroll
    for (int mi = 0; mi < 8; ++mi)
        #pragma unroll
        for (int ni = 0; ni < 4; ++ni) {
            f32x4 v = acc[mi][ni];
            #pragma unroll
            for (int r = 0; r < 4; ++r) {
                float e = __expf(v[r] * alpha);
                rs[mi][r] += e;
                const int row = mi * 16 + quad * 4 + r;
                const int col = ni * 16 + l16;
                scr[row * 64 + (((col >> 3) ^ (row & 7)) << 3) + (col & 7)] = f2bf(e);
            }
        }
    #pragma unroll
    for (int mi = 0; mi < 8; ++mi)
        #pragma unroll
        for (int r = 0; r < 4; ++r) {
            float s = rs[mi][r];
            s += __shfl_xor(s, 1); s += __shfl_xor(s, 2);
            s += __shfl_xor(s, 4); s += __shfl_xor(s, 8);
            if (l16 == 0)
                atomicAdd(&lsum[(long)z * 1024 + gm0 + mi * 16 + quad * 4 + r], s);
        }
    unsigned short* dst = Sb + (long)z * 1048576;
    #pragma unroll
    for (int it = 0; it < 16; ++it) {
        const int row = it * 8 + (lane >> 3);
        const int ck  = lane & 7;
        uint4 vv = *(uint4*)&scr[row * 64 + ((ck ^ (row & 7)) << 3)];
        *(uint4*)&dst[(long)(gm0 + row) * 1024 + gn0 + ck * 8] = vv;
    }
}

// ==========================================================================
// Fused QKV (128x256 8-phase): A = Wqkv [1536][512], B = xnT [n][c].
// blockIdx.y 0-3 -> qT (trans), 4-7 -> kT (trans), 8-11 -> vB (natural).
// grid (4,12,16) = 768 blocks = 3 exact rounds on 256 CUs.
// ==========================================================================
__global__ __launch_bounds__(512, 2) void qkv8_k(
    const unsigned short* __restrict__ Wqkv,
    const unsigned short* __restrict__ xnT,
    unsigned short* __restrict__ qT,
    unsigned short* __restrict__ kT,
    unsigned short* __restrict__ vB,
    const float* __restrict__ bqkv)
{
    __shared__ __align__(16) unsigned short LB[49152];   // 96 KB
    const int z = blockIdx.z;
    const unsigned short* Ab = Wqkv + (long)(blockIdx.y * 128) * 512;
    const unsigned short* Bb = xnT + (long)z * 524288 + (long)(blockIdx.x * 256) * 512;
    f32x4 acc[4][4] = {};
    gemm8_core<8, 1>(Ab, 512, Bb, 512, acc, LB);

    const int lane = threadIdx.x & 63, wave = threadIdx.x >> 6;
    const int wM = wave >> 2, wN = wave & 3;
    const int l16 = lane & 15, quad = lane >> 4;
    const int gm0 = blockIdx.y * 128 + wM * 64;
    const int gn0 = blockIdx.x * 256 + wN * 64;
    const int mat = blockIdx.y >> 2;            // 0=q 1=k 2=v (block-uniform)
    const int ml0 = gm0 & 511;
    const long zb = (long)z * 524288;
    unsigned short* scr = LB + wave * 4096;     // 8 KB per-wave scratch

    if (mat == 2) {
        // natural -> vB[c][j]; scratch [m 64][8 n-chunks of 8], XOR ml&7
        #pragma unroll
        for (int mi = 0; mi < 4; ++mi)
            #pragma unroll
            for (int ni = 0; ni < 4; ++ni) {
                f32x4 v = acc[mi][ni];
                #pragma unroll
                for (int r = 0; r < 4; ++r) {
                    const int ml = mi * 16 + quad * 4 + r;
                    const int nc = ni * 2 + (l16 >> 3);
                    scr[ml * 64 + ((nc ^ (ml & 7)) * 8) + (l16 & 7)] = f2bf(v[r] + bqkv[gm0 + ml]);
                }
            }
        const int ch2 = lane & 7, rr = lane >> 3;
        unsigned short* dst = vB + zb + gn0 + ch2 * 8;
        #pragma unroll
        for (int it = 0; it < 8; ++it) {
            const int ml = rr + it * 8;
            uint4 vv = *(uint4*)&scr[ml * 64 + ((ch2 ^ (ml & 7)) * 8)];
            *(uint4*)(dst + (long)(ml0 + ml) * 1024) = vv;
        }
    } else {
        // trans -> qT/kT [i][c]; scratch [n 64][8 m-chunks of 8], XOR nl&7
        unsigned short* dstm = (mat == 0) ? qT : kT;
        #pragma unroll
        for (int mi = 0; mi < 4; ++mi)
            #pragma unroll
            for (int ni = 0; ni < 4; ++ni) {
                f32x4 v = acc[mi][ni];
                const int nl = ni * 16 + l16;
                const int ch = mi * 2 + (quad >> 1);
                const int m4 = gm0 + mi * 16 + quad * 4;
                ushort4 p;
                p.x = f2bf(v[0] + bqkv[m4 + 0]);
                p.y = f2bf(v[1] + bqkv[m4 + 1]);
                p.z = f2bf(v[2] + bqkv[m4 + 2]);
                p.w = f2bf(v[3] + bqkv[m4 + 3]);
                *(ushort4*)&scr[nl * 64 + ((ch ^ (nl & 7)) * 8) + (quad & 1) * 4] = p;
            }
        const int ch2 = lane & 7, rr = lane >> 3;
        unsigned short* dst = dstm + zb + ml0 + ch2 * 8;
        #pragma unroll
        for (int it = 0; it < 8; ++it) {
            const int nl = rr + it * 8;
            uint4 vv = *(uint4*)&scr[nl * 64 + ((ch2 ^ (nl & 7)) * 8)];
            *(uint4*)(dst + (long)(gn0 + nl) * 512) = vv;
        }
    }
}

// ==========================================================================
// AV gemm (128x256 8-phase, K=1024): O[c][i] = sum_j vB[c][j]*Sb[i][j],
// scaled by 1/Lb[i], stored transposed -> OT[i][c].
// grid (4,4,16) = 256 blocks = 1 exact round.
// ==========================================================================
__global__ __launch_bounds__(512, 2) void av8_k(
    const unsigned short* __restrict__ vB,
    const unsigned short* __restrict__ Sb,
    unsigned short* __restrict__ OT,
    const float* __restrict__ Lb)
{
    __shared__ __align__(16) unsigned short LB[49152];   // 96 KB
    const int z = blockIdx.z;
    const unsigned short* Ab = vB + (long)z * 524288 + (long)(blockIdx.y * 128) * 1024;
    const unsigned short* Bb = Sb + (long)z * 1048576 + (long)(blockIdx.x * 256) * 1024;
    f32x4 acc[4][4] = {};
    gemm8_core<16, 1>(Ab, 1024, Bb, 1024, acc, LB);

    const int lane = threadIdx.x & 63, wave = threadIdx.x >> 6;
    const int wM = wave >> 2, wN = wave & 3;
    const int l16 = lane & 15, quad = lane >> 4;
    const int gm0 = blockIdx.y * 128 + wM * 64;   // c
    const int gn0 = blockIdx.x * 256 + wN * 64;   // i
    unsigned short* scr = LB + wave * 4096;

    #pragma unroll
    for (int mi = 0; mi < 4; ++mi)
        #pragma unroll
        for (int ni = 0; ni < 4; ++ni) {
            f32x4 v = acc[mi][ni];
            const float invl = 1.f / Lb[(long)z * 1024 + gn0 + ni * 16 + l16];
            const int nl = ni * 16 + l16;
            const int ch = mi * 2 + (quad >> 1);
            ushort4 p;
            p.x = f2bf(v[0] * invl); p.y = f2bf(v[1] * invl);
            p.z = f2bf(v[2] * invl); p.w = f2bf(v[3] * invl);
            *(ushort4*)&scr[nl * 64 + ((ch ^ (nl & 7)) * 8) + (quad & 1) * 4] = p;
        }
    const int ch2 = lane & 7, rr = lane >> 3;
    unsigned short* dst = OT + (long)z * 524288 + gm0 + ch2 * 8;
    #pragma unroll
    for (int it = 0; it < 8; ++it) {
        const int nl = rr + it * 8;
        uint4 vv = *(uint4*)&scr[nl * 64 + ((ch2 ^ (nl & 7)) * 8)];
        *(uint4*)(dst + (long)(gn0 + nl) * 512) = vv;
    }
}

// ==========================================================================
// ============== 128x128 2-phase core (final fp32 gemm) ====================
// ==========================================================================
__device__ __forceinline__ void stage_tiles(
    const unsigned short* __restrict__ Ab, int lda,
    const unsigned short* __restrict__ Bb, int ldb,
    int k0, unsigned short* Ad, unsigned short* Bd,
    int wave, int r0, int c0)
{
    gl_lds16(Ab + (long)r0 * lda + c0 + k0,        Ad + wave * 512);
    gl_lds16(Ab + (long)(r0 + 64) * lda + c0 + k0, Ad + 2048 + wave * 512);
    gl_lds16(Bb + (long)r0 * ldb + c0 + k0,        Bd + wave * 512);
    gl_lds16(Bb + (long)(r0 + 64) * ldb + c0 + k0, Bd + 2048 + wave * 512);
}

__device__ __forceinline__ void gemm_core_db(
    const unsigned short* __restrict__ Ab, int lda,
    const unsigned short* __restrict__ Bb, int ldb,
    int K, f32x4 (&acc)[4][4],
    unsigned short* As, unsigned short* Bs)   // As[2*4096], Bs[2*4096]
{
    const int tid  = threadIdx.x;
    const int lane = tid & 63;
    const int wave = tid >> 6;
    const int wm   = (wave >> 1) * 64;
    const int wn   = (wave & 1) * 64;
    const int l16  = lane & 15;
    const int quad = lane >> 4;

    const int r0 = wave * 16 + (lane >> 2);
    const int c0 = ((lane & 3) ^ ((lane >> 3) & 3)) * 8;   // source chunk pre-swizzle

    stage_tiles(Ab, lda, Bb, ldb, 0, As, Bs, wave, r0, c0);

    const int sw8 = ((l16 >> 1) & 3) * 8;     // read-side un-swizzle

    int sel = 0;
    for (int k0 = 0; k0 < K; k0 += 32) {
        __syncthreads();
        if (k0 + 32 < K)
            stage_tiles(Ab, lda, Bb, ldb, k0 + 32,
                        As + (sel ^ 1) * 4096, Bs + (sel ^ 1) * 4096, wave, r0, c0);

        const unsigned short* Ap = As + sel * 4096;
        const unsigned short* Bp = Bs + sel * 4096;
        bf16x8 af[4], bfr[4];
        #pragma unroll
        for (int mi = 0; mi < 4; mi++)
            af[mi] = *(const bf16x8*)&Ap[(wm + mi * 16 + l16) * 32 + ((quad * 8) ^ sw8)];
        #pragma unroll
        for (int ni = 0; ni < 4; ni++)
            bfr[ni] = *(const bf16x8*)&Bp[(wn + ni * 16 + l16) * 32 + ((quad * 8) ^ sw8)];
        #pragma unroll
        for (int mi = 0; mi < 4; mi++)
            #pragma unroll
            for (int ni = 0; ni < 4; ni++)
                acc[mi][ni] = __builtin_amdgcn_mfma_f32_16x16x32_bf16(af[mi], bfr[ni], acc[mi][ni], 0, 0, 0);
        sel ^= 1;
    }
}

// final gemm: out = Wp*OT^T + bp + x   (fp32 out, fully coalesced direct)
__global__ __launch_bounds__(256) void fin_k(
    const unsigned short* __restrict__ Wp,
    const unsigned short* __restrict__ OTb,
    float* __restrict__ out,
    const float* __restrict__ bias,
    const float* __restrict__ resid)
{
    __shared__ __align__(16) unsigned short LB[16384];   // 32 KB
    unsigned short* As = LB;
    unsigned short* Bs = LB + 8192;

    const unsigned short* Ab = Wp + (long)(blockIdx.y * 128) * 512;
    const unsigned short* Bb = OTb + (long)blockIdx.z * 524288 + (long)(blockIdx.x * 128) * 512;

    f32x4 acc[4][4] = {};
    gemm_core_db(Ab, 512, Bb, 512, 512, acc, As, Bs);

    const int lane = threadIdx.x & 63;
    const int wave = threadIdx.x >> 6;
    const int l16  = lane & 15;
    const int quad = lane >> 4;
    const int mb = blockIdx.y * 128 + (wave >> 1) * 64;
    const int nb = blockIdx.x * 128 + (wave & 1) * 64;

    #pragma unroll
    for (int mi = 0; mi < 4; mi++) {
        #pragma unroll
        for (int ni = 0; ni < 4; ni++) {
            f32x4 v = acc[mi][ni];
            const int m0 = mb + mi * 16 + quad * 4;
            const int n  = nb + ni * 16 + l16;
            const long base = (long)blockIdx.z * 524288;
            #pragma unroll
            for (int r = 0; r < 4; r++) {
                float val = v[r] + bias[m0 + r] + resid[base + (long)(m0 + r) * 1024 + n];
                out[base + (long)(m0 + r) * 1024 + n] = val;
            }
        }
    }
}

// ==========================================================================
// Merged GroupNorm + weight-conversion kernel (1D grid, 1792 blocks):
//   bid < 512 : GN  x[b][c][n] fp32 -> xnT[b][n][c] bf16 (b=bid>>5, g=bid&31)
//   bid >= 512: wconv (j = bid-512; m = j>>8 in 0..4, x-block = j&255)
// ==========================================================================
__global__ __launch_bounds__(256) void gnw_k(
    const float* __restrict__ x, const float* __restrict__ gsc,
    const float* __restrict__ gbi, unsigned short* __restrict__ xnT,
    const float* __restrict__ w0, const float* __restrict__ w1,
    const float* __restrict__ w2, const float* __restrict__ w3,
    const float* __restrict__ b0, const float* __restrict__ b1,
    const float* __restrict__ b2,
    unsigned short* __restrict__ wout, float* __restrict__ bqkv,
    float* __restrict__ lsum)
{
    __shared__ __align__(16) unsigned short ln[16 * 1024];
    __shared__ float red[8];
    const int bid = blockIdx.x;
    const int tid = threadIdx.x;

    if (bid >= 512) {                       // ---- wconv part ----
        const int j = bid - 512;
        const int m = j >> 8;
        const int i = (j & 255) * 256 + tid;
        if (m == 4) {
            if (i < 384) {
                const int which = i >> 7, off = i & 127;
                const float* src = (which == 0) ? b0 : (which == 1) ? b1 : b2;
                ((float4*)bqkv)[i] = ((const float4*)src)[off];
            }
            if (i < 16384) lsum[i] = 0.f;   // zero [16][1024] row-sum buffer
            return;
        }
        const float* src = (m == 0) ? w0 : (m == 1) ? w1 : (m == 2) ? w2 : w3;
        float4 v = ((const float4*)src)[i];
        ushort4 o; o.x = f2bf(v.x); o.y = f2bf(v.y); o.z = f2bf(v.z); o.w = f2bf(v.w);
        ((ushort4*)(wout + (long)m * 262144))[i] = o;
        return;
    }

    // ---- GN part ----
    const int b = bid >> 5, g = bid & 31;
    const int lane = tid & 63, wv = tid >> 6;

    const float4* x4 = (const float4*)(x + ((long)b * 512 + g * 16) * 1024);
    float4 vals[16];
    float s = 0.f, ss = 0.f;
    #pragma unroll
    for (int i = 0; i < 16; i++) {
        float4 v = x4[tid + i * 256];
        vals[i] = v;
        s  += v.x + v.y + v.z + v.w;
        ss += v.x * v.x + v.y * v.y + v.z * v.z + v.w * v.w;
    }
    for (int o = 32; o; o >>= 1) { s += __shfl_down(s, o); ss += __shfl_down(ss, o); }
    if (lane == 0) { red[wv * 2] = s; red[wv * 2 + 1] = ss; }
    __syncthreads();
    const float S  = red[0] + red[2] + red[4] + red[6];
    const float SS = red[1] + red[3] + red[5] + red[7];
    const float mean = S * (1.f / 16384.f);
    const float var  = SS * (1.f / 16384.f) - mean * mean;
    const float inv  = rsqrtf(var + 1e-5f);

    #pragma unroll
    for (int i = 0; i < 16; i++) {
        const int idx = tid + i * 256;
        const int c   = idx >> 8;
        const float sc = gsc[g * 16 + c] * inv;
        const float bi = gbi[g * 16 + c] - mean * sc;
        float4 v = vals[i];
        ushort4 p;
        p.x = f2bf(v.x * sc + bi); p.y = f2bf(v.y * sc + bi);
        p.z = f2bf(v.z * sc + bi); p.w = f2bf(v.w * sc + bi);
        ((ushort4*)ln)[idx] = p;
    }
    __syncthreads();

    unsigned short* op = xnT + (long)b * 1024 * 512 + g * 16;
    for (int rep = 0; rep < 4; rep++) {
        const int n = rep * 256 + tid;
        union { unsigned short u[16]; uint4 v[2]; } t;
        #pragma unroll
        for (int c = 0; c < 16; c++) t.u[c] = ln[c * 1024 + n];
        *(uint4*)&op[(long)n * 512]     = t.v[0];
        *(uint4*)&op[(long)n * 512 + 8] = t.v[1];
    }
}

// ==========================================================================
extern "C" void kernel_launch(void* const* d_in, const int* in_sizes, int n_in,
                              void* d_out, int out_size, void* d_ws, size_t ws_size,
                              hipStream_t stream)
{
    const float* x   = (const float*)d_in[0];
    const float* gsc = (const float*)d_in[1];
    const float* gbi = (const float*)d_in[2];
    const float* wq  = (const float*)d_in[3];
    const float* bq  = (const float*)d_in[4];
    const float* wk  = (const float*)d_in[5];
    const float* bk  = (const float*)d_in[6];
    const float* wv  = (const float*)d_in[7];
    const float* bv  = (const float*)d_in[8];
    const float* wp  = (const float*)d_in[9];
    const float* bp  = (const float*)d_in[10];
    float* out = (float*)d_out;

    char* ws = (char*)d_ws;
    unsigned short* xnT = (unsigned short*)(ws);               // 16 MB [b][n][c]; reused as OT
    unsigned short* qT  = (unsigned short*)(ws + 16777216);    // 16 MB [b][i][c]
    unsigned short* kT  = (unsigned short*)(ws + 33554432);    // 16 MB [b][j][c]
    unsigned short* vB  = (unsigned short*)(ws + 50331648);    // 16 MB [b][c][j]
    unsigned short* Sb  = (unsigned short*)(ws + 67108864);    // 32 MB [b][i][j] bf16 (P' = exp)
    unsigned short* Wb  = (unsigned short*)(ws + 100663296);   // 2 MB: wq|wk|wv|wp bf16
    float*          bqkv= (float*)        (ws + 102760448);    // 6 KB
    float*          Lb  = (float*)        (ws + 102768640);    // 64 KB [b][i] row sums
    unsigned short* OT  = xnT;

    // GN + weight conversion (merged)
    gnw_k<<<1792, 256, 0, stream>>>(x, gsc, gbi, xnT,
                                    wq, wk, wv, wp, bq, bk, bv, Wb, bqkv, Lb);

    // fused QKV (128x256 8-phase, 768 blocks = 3 rounds)
    qkv8_k<<<dim3(4, 12, 16), 512, 0, stream>>>(Wb, xnT, qT, kT, vB, bqkv);

    // P'[i][j] = exp(q·k/sqrt(512)) -> bf16 (256^2 8-phase, 256 blocks)
    p8_k<<<dim3(4, 4, 16), 512, 0, stream>>>(qT, kT, Sb, Lb, 0.044194173824159216f);

    // O = V·P'^T / L -> OT[i][c] (128x256 8-phase, K=1024, 256 blocks)
    av8_k<<<dim3(4, 4, 16), 512, 0, stream>>>(vB, Sb, OT, Lb);

    // out = Wp * O + bp + x
    fin_k<<<dim3(8, 4, 16), 256, 0, stream>>>(Wb + 786432, OT, out, bp, x);
}